// Round 2
// baseline (985.639 us; speedup 1.0000x reference)
//
#include <hip/hip_runtime.h>
#include <hip/hip_bf16.h>
#include <stdint.h>

#define N_TOK 4096
#define C_DIM 1024
#define F_DIM 2048
#define E_NUM 8
#define SMAX 9216       // 72 tiles * 128 rows: max padded slot count
#define TILES_MAX 72

typedef __attribute__((ext_vector_type(4))) float f32x4;
typedef __attribute__((ext_vector_type(8))) short s16x8;

__device__ __forceinline__ uint16_t f2bf(float f) {
    unsigned x;
    __builtin_memcpy(&x, &f, 4);
    unsigned r = (x + 0x7fffu + ((x >> 16) & 1u)) >> 16;  // RNE
    return (uint16_t)r;
}

#define GLL16(gp, lp)                                                                  \
    __builtin_amdgcn_global_load_lds((const __attribute__((address_space(1))) unsigned int*)(gp), \
                                     (__attribute__((address_space(3))) unsigned int*)(lp), 16, 0, 0)

// ---------------- router: fp32 logits -> softmax -> top2 -> counts + prob sums ----------------
__global__ void router_kernel(const float* __restrict__ x, const float* __restrict__ rw,
                              int* __restrict__ topk_idx, float* __restrict__ topk_w,
                              float* __restrict__ probs_sum, int* __restrict__ count) {
    int lane = threadIdx.x & 63;
    int wv = threadIdx.x >> 6;
    int t = blockIdx.x * 4 + wv;

    const float* xr = x + (size_t)t * C_DIM + lane * 16;
    float xs[16];
    for (int i = 0; i < 4; i++) *(float4*)&xs[i * 4] = *(const float4*)(xr + i * 4);

    float acc[E_NUM];
    for (int e = 0; e < E_NUM; e++) {
        const float* wr = rw + e * C_DIM + lane * 16;
        float s = 0.f;
        for (int i = 0; i < 4; i++) {
            float4 v = *(const float4*)(wr + i * 4);
            s += xs[i * 4] * v.x + xs[i * 4 + 1] * v.y + xs[i * 4 + 2] * v.z + xs[i * 4 + 3] * v.w;
        }
        acc[e] = s;
    }
    for (int off = 32; off > 0; off >>= 1)
        for (int e = 0; e < E_NUM; e++) acc[e] += __shfl_down(acc[e], off, 64);

    if (lane == 0) {
        float m = acc[0];
        for (int e = 1; e < E_NUM; e++) m = fmaxf(m, acc[e]);
        float p[E_NUM], s = 0.f;
        for (int e = 0; e < E_NUM; e++) { p[e] = __expf(acc[e] - m); s += p[e]; }
        float inv = 1.f / s;
        for (int e = 0; e < E_NUM; e++) { p[e] *= inv; atomicAdd(&probs_sum[e], p[e]); }
        int i0 = 0;
        for (int e = 1; e < E_NUM; e++) if (p[e] > p[i0]) i0 = e;         // ties -> lowest idx
        int i1 = (i0 == 0) ? 1 : 0;
        for (int e = 0; e < E_NUM; e++) if (e != i0 && p[e] > p[i1]) i1 = e;
        float w0 = p[i0], w1 = p[i1], wsum = w0 + w1;
        topk_idx[t * 2] = i0; topk_idx[t * 2 + 1] = i1;
        topk_w[t * 2] = w0 / wsum; topk_w[t * 2 + 1] = w1 / wsum;
        atomicAdd(&count[i0], 1); atomicAdd(&count[i1], 1);
    }
}

// ---------------- plan: 128-aligned per-expert slot ranges, tile map, aux loss (fp32) ----------------
__global__ void plan_kernel(const int* __restrict__ count, const float* __restrict__ probs_sum,
                            int* __restrict__ offsets, int* __restrict__ tile_expert,
                            int* __restrict__ tile_row0, float* __restrict__ aux_out) {
    if (threadIdx.x != 0 || blockIdx.x != 0) return;
    int off = 0, t = 0;
    for (int e = 0; e < E_NUM; e++) {
        offsets[e] = off;
        int n = count[e];
        int nt = (n + 127) >> 7;
        for (int i = 0; i < nt; i++) { tile_expert[t] = e; tile_row0[t] = off + i * 128; t++; }
        off += nt * 128;
    }
    offsets[E_NUM] = off;
    for (; t < TILES_MAX; t++) tile_expert[t] = -1;
    float s = 0.f;
    for (int e = 0; e < E_NUM; e++) { float a = probs_sum[e] * (1.f / N_TOK); s += a * a; }
    aux_out[0] = 8.f * s;
}

// ---------------- scatter: assign slots, gather+convert x rows (fp32 -> bf16) ----------------
__global__ void scatter_kernel(const float* __restrict__ x, const int* __restrict__ topk_idx,
                               const float* __restrict__ topk_w, const int* __restrict__ offsets,
                               int* __restrict__ count2, int* __restrict__ slot_map,
                               float* __restrict__ slot_w, uint16_t* __restrict__ x_slots) {
    int t = blockIdx.x >> 1, k = blockIdx.x & 1;
    __shared__ int s_slot;
    if (threadIdx.x == 0) {
        int e = topk_idx[t * 2 + k];
        int pos = atomicAdd(&count2[e], 1);
        int slot = offsets[e] + pos;
        slot_map[slot] = t * 2 + k;
        slot_w[slot] = topk_w[t * 2 + k];
        s_slot = slot;
    }
    __syncthreads();
    int slot = s_slot;
    float4 v = *(const float4*)(x + (size_t)t * C_DIM + threadIdx.x * 4);
    union { uint16_t u[4]; uint2 q; } r;
    r.u[0] = f2bf(v.x); r.u[1] = f2bf(v.y); r.u[2] = f2bf(v.z); r.u[3] = f2bf(v.w);
    *(uint2*)(x_slots + (size_t)slot * C_DIM + threadIdx.x * 4) = r.q;  // 256 thr * 4 elem = 1024
}

// ---------------- convert+transpose fp32 [R][Cc] -> bf16 [Cc][R] per expert z ----------------
__global__ void convT_kernel(const float* __restrict__ in, uint16_t* __restrict__ out,
                             int R, int Cc) {
    __shared__ uint16_t tile[32][33];
    size_t zb = (size_t)blockIdx.z * R * Cc;
    int c0 = blockIdx.x * 32, r0 = blockIdx.y * 32;
    int tx = threadIdx.x & 31, ty = threadIdx.x >> 5;
    for (int i = 0; i < 32; i += 8)
        tile[ty + i][tx] = f2bf(in[zb + (size_t)(r0 + ty + i) * Cc + c0 + tx]);
    __syncthreads();
    for (int i = 0; i < 32; i += 8)
        out[zb + (size_t)(c0 + ty + i) * R + r0 + tx] = tile[tx][ty + i];
}

// ---------------- GEMM1: act = swiglu(x_slots @ w_v[e]) ; 128 rows x (64 gate + 64 value) ----------------
__global__ __launch_bounds__(256) void gemm1_kernel(const uint16_t* __restrict__ x_slots,
                                                    const uint16_t* __restrict__ wvT,
                                                    const int* __restrict__ tile_expert,
                                                    const int* __restrict__ tile_row0,
                                                    uint16_t* __restrict__ act) {
    int e = tile_expert[blockIdx.y];
    if (e < 0) return;
    int row0 = tile_row0[blockIdx.y];
    int j = blockIdx.x;  // 0..31, gate cols [j*64, j*64+64)
    __shared__ uint16_t As[128 * 32];
    __shared__ uint16_t Bg[64 * 32];
    __shared__ uint16_t Bv[64 * 32];
    int lane = threadIdx.x & 63, w = threadIdx.x >> 6;
    int wm = w & 1, wn = w >> 1;
    const uint16_t* wvb = wvT + (size_t)e * 4096 * 1024;  // [n=4096][k=1024]

    int sk = (lane & 3) * 8;                  // bf16 offset within 32-k chunk
    int ar = w * 32 + (lane >> 2);            // A row, instr0
    const uint16_t* agp0 = x_slots + (size_t)(row0 + ar) * C_DIM + sk;
    const uint16_t* agp1 = agp0 + (size_t)16 * C_DIM;
    int br = w * 16 + (lane >> 2);            // B row (n) for this wave
    const uint16_t* bgp = wvb + (size_t)(j * 64 + br) * C_DIM + sk;
    const uint16_t* bvp = wvb + (size_t)(2048 + j * 64 + br) * C_DIM + sk;

    f32x4 accg[4][2], accv[4][2];
    f32x4 z4 = {0.f, 0.f, 0.f, 0.f};
    for (int mf = 0; mf < 4; mf++)
        for (int nf = 0; nf < 2; nf++) { accg[mf][nf] = z4; accv[mf][nf] = z4; }

    for (int kt = 0; kt < 32; ++kt) {
        int ko = kt * 32;
        __syncthreads();
        GLL16(agp0 + ko, As + w * 1024);
        GLL16(agp1 + ko, As + w * 1024 + 512);
        GLL16(bgp + ko, Bg + w * 512);
        GLL16(bvp + ko, Bv + w * 512);
        __syncthreads();
        s16x8 af[4], bg[2], bv[2];
        for (int mf = 0; mf < 4; mf++)
            af[mf] = *(const s16x8*)&As[(wm * 64 + mf * 16 + (lane & 15)) * 32 + (lane >> 4) * 8];
        for (int nf = 0; nf < 2; nf++) {
            bg[nf] = *(const s16x8*)&Bg[(wn * 32 + nf * 16 + (lane & 15)) * 32 + (lane >> 4) * 8];
            bv[nf] = *(const s16x8*)&Bv[(wn * 32 + nf * 16 + (lane & 15)) * 32 + (lane >> 4) * 8];
        }
        for (int mf = 0; mf < 4; mf++)
            for (int nf = 0; nf < 2; nf++) {
                accg[mf][nf] = __builtin_amdgcn_mfma_f32_16x16x32_bf16(af[mf], bg[nf], accg[mf][nf], 0, 0, 0);
                accv[mf][nf] = __builtin_amdgcn_mfma_f32_16x16x32_bf16(af[mf], bv[nf], accv[mf][nf], 0, 0, 0);
            }
    }
    for (int mf = 0; mf < 4; mf++)
        for (int nf = 0; nf < 2; nf++)
            for (int r = 0; r < 4; r++) {
                int row = row0 + wm * 64 + mf * 16 + (lane >> 4) * 4 + r;
                int col = j * 64 + wn * 32 + nf * 16 + (lane & 15);
                float g = accg[mf][nf][r], v = accv[mf][nf][r];
                float a = g * v / (1.f + __expf(-g));  // silu(g)*v
                act[(size_t)row * F_DIM + col] = f2bf(a);
            }
}

// ---------------- GEMM2: out[t] += weight * (act @ c_proj[e]) ; 128x128 tile, fp32 atomics ----------------
__global__ __launch_bounds__(256) void gemm2_kernel(const uint16_t* __restrict__ act,
                                                    const uint16_t* __restrict__ cpT,
                                                    const int* __restrict__ tile_expert,
                                                    const int* __restrict__ tile_row0,
                                                    const int* __restrict__ slot_map,
                                                    const float* __restrict__ slot_w,
                                                    float* __restrict__ out) {
    int e = tile_expert[blockIdx.y];
    if (e < 0) return;
    int row0 = tile_row0[blockIdx.y];
    int cb = blockIdx.x * 128;
    __shared__ uint16_t As[128 * 32];
    __shared__ uint16_t Bs[128 * 32];
    int lane = threadIdx.x & 63, w = threadIdx.x >> 6;
    int wm = w & 1, wn = w >> 1;
    const uint16_t* cpb = cpT + (size_t)e * 1024 * 2048;  // [n=1024][k=2048]

    int sk = (lane & 3) * 8;
    int ar = w * 32 + (lane >> 2);
    const uint16_t* agp0 = act + (size_t)(row0 + ar) * F_DIM + sk;
    const uint16_t* agp1 = agp0 + (size_t)16 * F_DIM;
    const uint16_t* bgp0 = cpb + (size_t)(cb + ar) * F_DIM + sk;
    const uint16_t* bgp1 = bgp0 + (size_t)16 * F_DIM;

    f32x4 acc[4][4];
    f32x4 z4 = {0.f, 0.f, 0.f, 0.f};
    for (int mf = 0; mf < 4; mf++)
        for (int nf = 0; nf < 4; nf++) acc[mf][nf] = z4;

    for (int kt = 0; kt < 64; ++kt) {
        int ko = kt * 32;
        __syncthreads();
        GLL16(agp0 + ko, As + w * 1024);
        GLL16(agp1 + ko, As + w * 1024 + 512);
        GLL16(bgp0 + ko, Bs + w * 1024);
        GLL16(bgp1 + ko, Bs + w * 1024 + 512);
        __syncthreads();
        s16x8 af[4], bf[4];
        for (int mf = 0; mf < 4; mf++)
            af[mf] = *(const s16x8*)&As[(wm * 64 + mf * 16 + (lane & 15)) * 32 + (lane >> 4) * 8];
        for (int nf = 0; nf < 4; nf++)
            bf[nf] = *(const s16x8*)&Bs[(wn * 64 + nf * 16 + (lane & 15)) * 32 + (lane >> 4) * 8];
        for (int mf = 0; mf < 4; mf++)
            for (int nf = 0; nf < 4; nf++)
                acc[mf][nf] = __builtin_amdgcn_mfma_f32_16x16x32_bf16(af[mf], bf[nf], acc[mf][nf], 0, 0, 0);
    }
    for (int mf = 0; mf < 4; mf++)
        for (int r = 0; r < 4; r++) {
            int slotr = row0 + wm * 64 + mf * 16 + (lane >> 4) * 4 + r;
            int t2k = slot_map[slotr];
            if (t2k < 0) continue;  // padding row
            float wgt = slot_w[slotr];
            int t = t2k >> 1;
            for (int nf = 0; nf < 4; nf++) {
                int col = cb + wn * 64 + nf * 16 + (lane & 15);
                atomicAdd(&out[(size_t)t * C_DIM + col], wgt * acc[mf][nf][r]);
            }
        }
}

extern "C" void kernel_launch(void* const* d_in, const int* in_sizes, int n_in,
                              void* d_out, int out_size, void* d_ws, size_t ws_size,
                              hipStream_t stream) {
    (void)in_sizes; (void)n_in; (void)out_size; (void)ws_size;
    const float* x = (const float*)d_in[0];
    const float* rw = (const float*)d_in[1];
    const float* wv = (const float*)d_in[2];
    const float* cp = (const float*)d_in[3];
    float* out = (float*)d_out;

    char* ws = (char*)d_ws;
    size_t off = 0;
    auto alloc = [&](size_t sz) -> void* {
        off = (off + 255) & ~(size_t)255;
        void* p = ws + off;
        off += sz;
        return p;
    };
    uint16_t* wvT = (uint16_t*)alloc((size_t)E_NUM * 4096 * 1024 * 2);   // 64 MB
    uint16_t* cpT = (uint16_t*)alloc((size_t)E_NUM * 1024 * 2048 * 2);   // 32 MB
    uint16_t* x_slots = (uint16_t*)alloc((size_t)SMAX * C_DIM * 2);      // ~19 MB
    uint16_t* act = (uint16_t*)alloc((size_t)SMAX * F_DIM * 2);          // ~38 MB
    float* probs_sum = (float*)alloc(E_NUM * 4);
    int* count = (int*)alloc(E_NUM * 4);
    int* count2 = (int*)alloc(E_NUM * 4);
    int* offsets = (int*)alloc((E_NUM + 1) * 4);
    int* tile_expert = (int*)alloc(TILES_MAX * 4);
    int* tile_row0 = (int*)alloc(TILES_MAX * 4);
    int* topk_idx = (int*)alloc((size_t)N_TOK * 2 * 4);
    float* topk_w = (float*)alloc((size_t)N_TOK * 2 * 4);
    int* slot_map = (int*)alloc((size_t)SMAX * 4);
    float* slot_w = (float*)alloc((size_t)SMAX * 4);

    hipMemsetAsync(probs_sum, 0, E_NUM * 4, stream);
    hipMemsetAsync(count, 0, E_NUM * 4, stream);
    hipMemsetAsync(count2, 0, E_NUM * 4, stream);
    hipMemsetAsync(slot_map, 0xFF, (size_t)SMAX * 4, stream);  // -1 => padding
    hipMemsetAsync(out, 0, ((size_t)N_TOK * C_DIM + 1) * 4, stream);

    router_kernel<<<N_TOK / 4, 256, 0, stream>>>(x, rw, topk_idx, topk_w, probs_sum, count);
    plan_kernel<<<1, 64, 0, stream>>>(count, probs_sum, offsets, tile_expert, tile_row0,
                                      out + (size_t)N_TOK * C_DIM);
    scatter_kernel<<<N_TOK * 2, 256, 0, stream>>>(x, topk_idx, topk_w, offsets, count2,
                                                  slot_map, slot_w, x_slots);
    convT_kernel<<<dim3(4096 / 32, 1024 / 32, E_NUM), 256, 0, stream>>>(wv, wvT, 1024, 4096);
    convT_kernel<<<dim3(1024 / 32, 2048 / 32, E_NUM), 256, 0, stream>>>(cp, cpT, 2048, 1024);
    gemm1_kernel<<<dim3(32, TILES_MAX), 256, 0, stream>>>(x_slots, wvT, tile_expert, tile_row0, act);
    gemm2_kernel<<<dim3(8, TILES_MAX), 256, 0, stream>>>(act, cpT, tile_expert, tile_row0,
                                                         slot_map, slot_w, out);
}

// Round 3
// 492.363 us; speedup vs baseline: 2.0019x; 2.0019x over previous
//
#include <hip/hip_runtime.h>
#include <hip/hip_bf16.h>
#include <stdint.h>

#define N_TOK 4096
#define C_DIM 1024
#define F_DIM 2048
#define E_NUM 8
#define SMAX 9216       // 72 tiles * 128 rows: max padded slot count
#define TILES_MAX 72
#define RBLK 1024       // router blocks (4 tokens each)

typedef __attribute__((ext_vector_type(4))) float f32x4;
typedef __attribute__((ext_vector_type(8))) short s16x8;

__device__ __forceinline__ uint16_t f2bf(float f) {
    unsigned x;
    __builtin_memcpy(&x, &f, 4);
    unsigned r = (x + 0x7fffu + ((x >> 16) & 1u)) >> 16;  // RNE
    return (uint16_t)r;
}

#define GLL16(gp, lp)                                                                  \
    __builtin_amdgcn_global_load_lds((const __attribute__((address_space(1))) unsigned int*)(gp), \
                                     (__attribute__((address_space(3))) unsigned int*)(lp), 16, 0, 0)

// ---------------- router: fp32 logits -> softmax -> top2; LDS-aggregated partials, NO global atomics ----------------
__global__ void router_kernel(const float* __restrict__ x, const float* __restrict__ rw,
                              int* __restrict__ topk_idx, float* __restrict__ topk_w,
                              float* __restrict__ psum_part, int* __restrict__ cnt_part) {
    __shared__ float s_p[E_NUM];
    __shared__ int s_c[E_NUM];
    if (threadIdx.x < E_NUM) { s_p[threadIdx.x] = 0.f; s_c[threadIdx.x] = 0; }
    __syncthreads();

    int lane = threadIdx.x & 63;
    int wv = threadIdx.x >> 6;
    int t = blockIdx.x * 4 + wv;

    const float* xr = x + (size_t)t * C_DIM + lane * 16;
    float xs[16];
    for (int i = 0; i < 4; i++) *(float4*)&xs[i * 4] = *(const float4*)(xr + i * 4);

    float acc[E_NUM];
    for (int e = 0; e < E_NUM; e++) {
        const float* wr = rw + e * C_DIM + lane * 16;
        float s = 0.f;
        for (int i = 0; i < 4; i++) {
            float4 v = *(const float4*)(wr + i * 4);
            s += xs[i * 4] * v.x + xs[i * 4 + 1] * v.y + xs[i * 4 + 2] * v.z + xs[i * 4 + 3] * v.w;
        }
        acc[e] = s;
    }
    for (int off = 32; off > 0; off >>= 1)
        for (int e = 0; e < E_NUM; e++) acc[e] += __shfl_down(acc[e], off, 64);

    if (lane == 0) {
        float m = acc[0];
        for (int e = 1; e < E_NUM; e++) m = fmaxf(m, acc[e]);
        float p[E_NUM], s = 0.f;
        for (int e = 0; e < E_NUM; e++) { p[e] = __expf(acc[e] - m); s += p[e]; }
        float inv = 1.f / s;
        for (int e = 0; e < E_NUM; e++) { p[e] *= inv; atomicAdd(&s_p[e], p[e]); }  // LDS atomic
        int i0 = 0;
        for (int e = 1; e < E_NUM; e++) if (p[e] > p[i0]) i0 = e;         // ties -> lowest idx
        int i1 = (i0 == 0) ? 1 : 0;
        for (int e = 0; e < E_NUM; e++) if (e != i0 && p[e] > p[i1]) i1 = e;
        float w0 = p[i0], w1 = p[i1], wsum = w0 + w1;
        topk_idx[t * 2] = i0; topk_idx[t * 2 + 1] = i1;
        topk_w[t * 2] = w0 / wsum; topk_w[t * 2 + 1] = w1 / wsum;
        atomicAdd(&s_c[i0], 1); atomicAdd(&s_c[i1], 1);                   // LDS atomic
    }
    __syncthreads();
    if (threadIdx.x < E_NUM) {
        psum_part[blockIdx.x * E_NUM + threadIdx.x] = s_p[threadIdx.x];
        cnt_part[blockIdx.x * E_NUM + threadIdx.x] = s_c[threadIdx.x];
    }
}

// ---------------- reduce partials -> counts/psum; plan offsets+tiles; aux loss ----------------
__global__ void reduce_plan_kernel(const float* __restrict__ psum_part, const int* __restrict__ cnt_part,
                                   int* __restrict__ offsets, int* __restrict__ tile_expert,
                                   int* __restrict__ tile_row0, float* __restrict__ aux_out) {
    __shared__ float sp[256];
    __shared__ int sc[256];
    __shared__ int s_count[E_NUM];
    __shared__ float s_psum[E_NUM];
    int e = threadIdx.x >> 5, i = threadIdx.x & 31;
    float fp = 0.f; int c = 0;
    for (int j = i; j < RBLK; j += 32) { fp += psum_part[j * E_NUM + e]; c += cnt_part[j * E_NUM + e]; }
    sp[threadIdx.x] = fp; sc[threadIdx.x] = c;
    __syncthreads();
    for (int s = 16; s > 0; s >>= 1) {
        if (i < s) { sp[threadIdx.x] += sp[threadIdx.x + s]; sc[threadIdx.x] += sc[threadIdx.x + s]; }
        __syncthreads();
    }
    if (i == 0) { s_count[e] = sc[threadIdx.x]; s_psum[e] = sp[threadIdx.x]; }
    __syncthreads();
    if (threadIdx.x == 0) {
        int off = 0, t = 0;
        for (int ee = 0; ee < E_NUM; ee++) {
            offsets[ee] = off;
            int n = s_count[ee];
            int nt = (n + 127) >> 7;
            for (int k = 0; k < nt; k++) { tile_expert[t] = ee; tile_row0[t] = off + k * 128; t++; }
            off += nt * 128;
        }
        offsets[E_NUM] = off;
        for (; t < TILES_MAX; t++) tile_expert[t] = -1;
        float s = 0.f;
        for (int ee = 0; ee < E_NUM; ee++) { float a = s_psum[ee] * (1.f / N_TOK); s += a * a; }
        aux_out[0] = 8.f * s;
    }
}

// ---------------- assign: block-aggregated slot reservation (8 global atomics/block) ----------------
__global__ void assign_kernel(const int* __restrict__ topk_idx, const float* __restrict__ topk_w,
                              const int* __restrict__ offsets, int* __restrict__ count2,
                              int* __restrict__ slot_map, float* __restrict__ slot_w) {
    __shared__ int h[E_NUM];
    __shared__ int base[E_NUM];
    if (threadIdx.x < E_NUM) h[threadIdx.x] = 0;
    __syncthreads();
    int item = blockIdx.x * 256 + threadIdx.x;
    int e = topk_idx[item];
    int rank = atomicAdd(&h[e], 1);         // LDS atomic
    __syncthreads();
    if (threadIdx.x < E_NUM)
        base[threadIdx.x] = offsets[threadIdx.x] + atomicAdd(&count2[threadIdx.x], h[threadIdx.x]);
    __syncthreads();
    int slot = base[e] + rank;
    slot_map[slot] = item;
    slot_w[slot] = topk_w[item];
}

// ---------------- gather: copy+convert x rows (fp32 -> bf16) into slot space ----------------
__global__ void gather_kernel(const float* __restrict__ x, const int* __restrict__ slot_map,
                              uint16_t* __restrict__ x_slots) {
    int slot = blockIdx.x;
    int item = slot_map[slot];
    if (item < 0) return;  // padding row: leave poison (tiny denormals, harmless)
    int t = item >> 1;
    float4 v = *(const float4*)(x + (size_t)t * C_DIM + threadIdx.x * 4);
    union { uint16_t u[4]; uint2 q; } r;
    r.u[0] = f2bf(v.x); r.u[1] = f2bf(v.y); r.u[2] = f2bf(v.z); r.u[3] = f2bf(v.w);
    *(uint2*)(x_slots + (size_t)slot * C_DIM + threadIdx.x * 4) = r.q;
}

// ---------------- convert+transpose fp32 [R][Cc] -> bf16 [Cc][R] per expert z ----------------
__global__ void convT_kernel(const float* __restrict__ in, uint16_t* __restrict__ out,
                             int R, int Cc) {
    __shared__ uint16_t tile[32][33];
    size_t zb = (size_t)blockIdx.z * R * Cc;
    int c0 = blockIdx.x * 32, r0 = blockIdx.y * 32;
    int tx = threadIdx.x & 31, ty = threadIdx.x >> 5;
    for (int i = 0; i < 32; i += 8)
        tile[ty + i][tx] = f2bf(in[zb + (size_t)(r0 + ty + i) * Cc + c0 + tx]);
    __syncthreads();
    for (int i = 0; i < 32; i += 8)
        out[zb + (size_t)(c0 + ty + i) * R + r0 + tx] = tile[tx][ty + i];
}

// ---------------- GEMM1: act = swiglu(x_slots @ w_v[e]) ; 128 rows x (64 gate + 64 value) ----------------
__global__ __launch_bounds__(256) void gemm1_kernel(const uint16_t* __restrict__ x_slots,
                                                    const uint16_t* __restrict__ wvT,
                                                    const int* __restrict__ tile_expert,
                                                    const int* __restrict__ tile_row0,
                                                    uint16_t* __restrict__ act) {
    int e = tile_expert[blockIdx.y];
    if (e < 0) return;
    int row0 = tile_row0[blockIdx.y];
    int j = blockIdx.x;  // 0..31, gate cols [j*64, j*64+64)
    __shared__ uint16_t As[128 * 32];
    __shared__ uint16_t Bg[64 * 32];
    __shared__ uint16_t Bv[64 * 32];
    int lane = threadIdx.x & 63, w = threadIdx.x >> 6;
    int wm = w & 1, wn = w >> 1;
    const uint16_t* wvb = wvT + (size_t)e * 4096 * 1024;  // [n=4096][k=1024]

    int sk = (lane & 3) * 8;                  // bf16 offset within 32-k chunk
    int ar = w * 32 + (lane >> 2);            // A row, instr0
    const uint16_t* agp0 = x_slots + (size_t)(row0 + ar) * C_DIM + sk;
    const uint16_t* agp1 = agp0 + (size_t)16 * C_DIM;
    int br = w * 16 + (lane >> 2);            // B row (n) for this wave
    const uint16_t* bgp = wvb + (size_t)(j * 64 + br) * C_DIM + sk;
    const uint16_t* bvp = wvb + (size_t)(2048 + j * 64 + br) * C_DIM + sk;

    f32x4 accg[4][2], accv[4][2];
    f32x4 z4 = {0.f, 0.f, 0.f, 0.f};
    for (int mf = 0; mf < 4; mf++)
        for (int nf = 0; nf < 2; nf++) { accg[mf][nf] = z4; accv[mf][nf] = z4; }

    for (int kt = 0; kt < 32; ++kt) {
        int ko = kt * 32;
        __syncthreads();
        GLL16(agp0 + ko, As + w * 1024);
        GLL16(agp1 + ko, As + w * 1024 + 512);
        GLL16(bgp + ko, Bg + w * 512);
        GLL16(bvp + ko, Bv + w * 512);
        __syncthreads();
        s16x8 af[4], bg[2], bv[2];
        for (int mf = 0; mf < 4; mf++)
            af[mf] = *(const s16x8*)&As[(wm * 64 + mf * 16 + (lane & 15)) * 32 + (lane >> 4) * 8];
        for (int nf = 0; nf < 2; nf++) {
            bg[nf] = *(const s16x8*)&Bg[(wn * 32 + nf * 16 + (lane & 15)) * 32 + (lane >> 4) * 8];
            bv[nf] = *(const s16x8*)&Bv[(wn * 32 + nf * 16 + (lane & 15)) * 32 + (lane >> 4) * 8];
        }
        for (int mf = 0; mf < 4; mf++)
            for (int nf = 0; nf < 2; nf++) {
                accg[mf][nf] = __builtin_amdgcn_mfma_f32_16x16x32_bf16(af[mf], bg[nf], accg[mf][nf], 0, 0, 0);
                accv[mf][nf] = __builtin_amdgcn_mfma_f32_16x16x32_bf16(af[mf], bv[nf], accv[mf][nf], 0, 0, 0);
            }
    }
    for (int mf = 0; mf < 4; mf++)
        for (int nf = 0; nf < 2; nf++)
            for (int r = 0; r < 4; r++) {
                int row = row0 + wm * 64 + mf * 16 + (lane >> 4) * 4 + r;
                int col = j * 64 + wn * 32 + nf * 16 + (lane & 15);
                float g = accg[mf][nf][r], v = accv[mf][nf][r];
                float a = g * v / (1.f + __expf(-g));  // silu(g)*v
                act[(size_t)row * F_DIM + col] = f2bf(a);
            }
}

// ---------------- GEMM2: out[t] += weight * (act @ c_proj[e]) ; 128x128 tile, fp32 atomics ----------------
__global__ __launch_bounds__(256) void gemm2_kernel(const uint16_t* __restrict__ act,
                                                    const uint16_t* __restrict__ cpT,
                                                    const int* __restrict__ tile_expert,
                                                    const int* __restrict__ tile_row0,
                                                    const int* __restrict__ slot_map,
                                                    const float* __restrict__ slot_w,
                                                    float* __restrict__ out) {
    int e = tile_expert[blockIdx.y];
    if (e < 0) return;
    int row0 = tile_row0[blockIdx.y];
    int cb = blockIdx.x * 128;
    __shared__ uint16_t As[128 * 32];
    __shared__ uint16_t Bs[128 * 32];
    int lane = threadIdx.x & 63, w = threadIdx.x >> 6;
    int wm = w & 1, wn = w >> 1;
    const uint16_t* cpb = cpT + (size_t)e * 1024 * 2048;  // [n=1024][k=2048]

    int sk = (lane & 3) * 8;
    int ar = w * 32 + (lane >> 2);
    const uint16_t* agp0 = act + (size_t)(row0 + ar) * F_DIM + sk;
    const uint16_t* agp1 = agp0 + (size_t)16 * F_DIM;
    const uint16_t* bgp0 = cpb + (size_t)(cb + ar) * F_DIM + sk;
    const uint16_t* bgp1 = bgp0 + (size_t)16 * F_DIM;

    f32x4 acc[4][4];
    f32x4 z4 = {0.f, 0.f, 0.f, 0.f};
    for (int mf = 0; mf < 4; mf++)
        for (int nf = 0; nf < 4; nf++) acc[mf][nf] = z4;

    for (int kt = 0; kt < 64; ++kt) {
        int ko = kt * 32;
        __syncthreads();
        GLL16(agp0 + ko, As + w * 1024);
        GLL16(agp1 + ko, As + w * 1024 + 512);
        GLL16(bgp0 + ko, Bs + w * 1024);
        GLL16(bgp1 + ko, Bs + w * 1024 + 512);
        __syncthreads();
        s16x8 af[4], bf[4];
        for (int mf = 0; mf < 4; mf++)
            af[mf] = *(const s16x8*)&As[(wm * 64 + mf * 16 + (lane & 15)) * 32 + (lane >> 4) * 8];
        for (int nf = 0; nf < 4; nf++)
            bf[nf] = *(const s16x8*)&Bs[(wn * 64 + nf * 16 + (lane & 15)) * 32 + (lane >> 4) * 8];
        for (int mf = 0; mf < 4; mf++)
            for (int nf = 0; nf < 4; nf++)
                acc[mf][nf] = __builtin_amdgcn_mfma_f32_16x16x32_bf16(af[mf], bf[nf], acc[mf][nf], 0, 0, 0);
    }
    for (int mf = 0; mf < 4; mf++)
        for (int r = 0; r < 4; r++) {
            int slotr = row0 + wm * 64 + mf * 16 + (lane >> 4) * 4 + r;
            int t2k = slot_map[slotr];
            if (t2k < 0) continue;  // padding row
            float wgt = slot_w[slotr];
            int t = t2k >> 1;
            for (int nf = 0; nf < 4; nf++) {
                int col = cb + wn * 64 + nf * 16 + (lane & 15);
                atomicAdd(&out[(size_t)t * C_DIM + col], wgt * acc[mf][nf][r]);
            }
        }
}

extern "C" void kernel_launch(void* const* d_in, const int* in_sizes, int n_in,
                              void* d_out, int out_size, void* d_ws, size_t ws_size,
                              hipStream_t stream) {
    (void)in_sizes; (void)n_in; (void)out_size; (void)ws_size;
    const float* x = (const float*)d_in[0];
    const float* rw = (const float*)d_in[1];
    const float* wv = (const float*)d_in[2];
    const float* cp = (const float*)d_in[3];
    float* out = (float*)d_out;

    char* ws = (char*)d_ws;
    size_t off = 0;
    auto alloc = [&](size_t sz) -> void* {
        off = (off + 255) & ~(size_t)255;
        void* p = ws + off;
        off += sz;
        return p;
    };
    uint16_t* wvT = (uint16_t*)alloc((size_t)E_NUM * 4096 * 1024 * 2);   // 64 MB
    uint16_t* cpT = (uint16_t*)alloc((size_t)E_NUM * 1024 * 2048 * 2);   // 32 MB
    uint16_t* x_slots = (uint16_t*)alloc((size_t)SMAX * C_DIM * 2);      // ~19 MB
    uint16_t* act = (uint16_t*)alloc((size_t)SMAX * F_DIM * 2);          // ~38 MB
    float* psum_part = (float*)alloc((size_t)RBLK * E_NUM * 4);
    int* cnt_part = (int*)alloc((size_t)RBLK * E_NUM * 4);
    int* count2 = (int*)alloc(E_NUM * 4);
    int* offsets = (int*)alloc((E_NUM + 1) * 4);
    int* tile_expert = (int*)alloc(TILES_MAX * 4);
    int* tile_row0 = (int*)alloc(TILES_MAX * 4);
    int* topk_idx = (int*)alloc((size_t)N_TOK * 2 * 4);
    float* topk_w = (float*)alloc((size_t)N_TOK * 2 * 4);
    int* slot_map = (int*)alloc((size_t)SMAX * 4);
    float* slot_w = (float*)alloc((size_t)SMAX * 4);

    hipMemsetAsync(count2, 0, E_NUM * 4, stream);
    hipMemsetAsync(slot_map, 0xFF, (size_t)SMAX * 4, stream);  // -1 => padding
    hipMemsetAsync(out, 0, ((size_t)N_TOK * C_DIM + 1) * 4, stream);

    router_kernel<<<RBLK, 256, 0, stream>>>(x, rw, topk_idx, topk_w, psum_part, cnt_part);
    reduce_plan_kernel<<<1, 256, 0, stream>>>(psum_part, cnt_part, offsets, tile_expert, tile_row0,
                                              out + (size_t)N_TOK * C_DIM);
    assign_kernel<<<N_TOK * 2 / 256, 256, 0, stream>>>(topk_idx, topk_w, offsets, count2,
                                                       slot_map, slot_w);
    gather_kernel<<<SMAX, 256, 0, stream>>>(x, slot_map, x_slots);
    convT_kernel<<<dim3(4096 / 32, 1024 / 32, E_NUM), 256, 0, stream>>>(wv, wvT, 1024, 4096);
    convT_kernel<<<dim3(1024 / 32, 2048 / 32, E_NUM), 256, 0, stream>>>(cp, cpT, 2048, 1024);
    gemm1_kernel<<<dim3(32, TILES_MAX), 256, 0, stream>>>(x_slots, wvT, tile_expert, tile_row0, act);
    gemm2_kernel<<<dim3(8, TILES_MAX), 256, 0, stream>>>(act, cpT, tile_expert, tile_row0,
                                                         slot_map, slot_w, out);
}